// Round 3
// baseline (692.928 us; speedup 1.0000x reference)
//
#include <hip/hip_runtime.h>
#include <stdint.h>
#include <math.h>

#define L_DIM 3
#define B_DIM 64
#define P_DIM 225
#define D_DIM 640
#define R_DIM 1800
#define S_DIM 240
#define M_TOT (B_DIM * P_DIM)   /* 14400 */
#define M_PAD 14464             /* 113*128 (pmax sizing only) */
#define MT 113
#define NT 15
#define KSTEPS (D_DIM / 32)     /* 20 */
#define BNSCALE 0.99999500003749981f  /* 1/sqrt(1+1e-5) */

typedef __bf16 bf16x8 __attribute__((ext_vector_type(8)));
typedef __bf16 bf16x4 __attribute__((ext_vector_type(4)));
typedef float f32x4 __attribute__((ext_vector_type(4)));
typedef float fvec4 __attribute__((ext_vector_type(4)));

// ---------------------------------------------------------------- K0: norms
// one wave per A row: rnorm[l*M_TOT + r] = rsqrt(sum(x^2))
__global__ __launch_bounds__(256)
void k_norms(const float* __restrict__ pe, float* __restrict__ rnorm)
{
    int wid = (blockIdx.x * 256 + threadIdx.x) >> 6;   // 0 .. L*M_TOT-1
    int lane = threadIdx.x & 63;
    const float* src = pe + (size_t)wid * D_DIM;
    float ss = 0.f;
    #pragma unroll
    for (int it = 0; it < 5; ++it) {
        float2 v = *(const float2*)(src + it * 128 + lane * 2);
        ss += v.x * v.x + v.y * v.y;
    }
    #pragma unroll
    for (int m = 32; m; m >>= 1) ss += __shfl_xor(ss, m);
    if (lane == 0) rnorm[wid] = rsqrtf(ss);
}

// ----------------------------------------------------- K1: GEMM + fused rowmax
// 128x128 tile, 4 waves (2x2 of 64x64), BK=32, reg-staged f32->bf16 ds_write,
// mfma_f32_16x16x32_bf16. Reads pe/per f32 directly (LLC-resident re-reads).
__global__ __launch_bounds__(256)
void k_gemm_max(const float* __restrict__ pe, const float* __restrict__ per,
                float* __restrict__ pmax)
{
    __shared__ alignas(16) unsigned short ldsA[128 * 32];
    __shared__ alignas(16) unsigned short ldsB[128 * 32];
    __shared__ float red[2][128];

    int bid = blockIdx.x;
    int l = bid / (MT * NT);
    int rem = bid - l * (MT * NT);
    int mt = rem / NT;
    int nt = rem - mt * NT;

    int tid = threadIdx.x;
    int wave = tid >> 6, lane = tid & 63;
    int wm = wave >> 1, wn = wave & 1;

    const float* gA = pe + (size_t)l * M_TOT * D_DIM;
    const float* gB = per + (size_t)l * R_DIM * D_DIM;

    // staging map: float4 slot f = i*256+tid -> tile row f>>3, 16B-seg f&7
    const float* pa[4]; const float* pb[4];
    bool va[4], vb[4];
    int lofs[4];
    #pragma unroll
    for (int i = 0; i < 4; ++i) {
        int f = i * 256 + tid;
        int row = f >> 3, seg = f & 7;
        lofs[i] = row * 32 + seg * 4;                 // LDS element offset
        int gar = mt * 128 + row;
        int gbr = nt * 128 + row;
        va[i] = gar < M_TOT;
        vb[i] = gbr < R_DIM;
        pa[i] = gA + (size_t)(va[i] ? gar : 0) * D_DIM + seg * 4;
        pb[i] = gB + (size_t)(vb[i] ? gbr : 0) * D_DIM + seg * 4;
    }

    f32x4 acc[4][4];
    #pragma unroll
    for (int i = 0; i < 4; ++i)
        #pragma unroll
        for (int j = 0; j < 4; ++j)
            acc[i][j] = f32x4{0.f, 0.f, 0.f, 0.f};

    int arow = wm * 64 + (lane & 15);
    int brow = wn * 64 + (lane & 15);
    int kgrp = (lane >> 4) * 8;

    fvec4 ra[4], rb[4];
    const fvec4 z4 = fvec4{0.f, 0.f, 0.f, 0.f};
    #pragma unroll
    for (int i = 0; i < 4; ++i) {
        ra[i] = va[i] ? *(const fvec4*)(pa[i]) : z4;
        rb[i] = vb[i] ? *(const fvec4*)(pb[i]) : z4;
    }

    for (int ks = 0; ks < KSTEPS; ++ks) {
        __syncthreads();   // prior iteration's frag reads complete
        #pragma unroll
        for (int i = 0; i < 4; ++i) {
            *(bf16x4*)(ldsA + lofs[i]) = __builtin_convertvector(ra[i], bf16x4);
            *(bf16x4*)(ldsB + lofs[i]) = __builtin_convertvector(rb[i], bf16x4);
        }
        __syncthreads();
        if (ks + 1 < KSTEPS) {     // prefetch next K-slab; overlaps MFMA below
            int off = (ks + 1) * 32;
            #pragma unroll
            for (int i = 0; i < 4; ++i) {
                ra[i] = va[i] ? *(const fvec4*)(pa[i] + off) : z4;
                rb[i] = vb[i] ? *(const fvec4*)(pb[i] + off) : z4;
            }
        }
        bf16x8 afr[4], bfr[4];
        #pragma unroll
        for (int i = 0; i < 4; ++i)
            afr[i] = *(const bf16x8*)(ldsA + (arow + i * 16) * 32 + kgrp);
        #pragma unroll
        for (int j = 0; j < 4; ++j)
            bfr[j] = *(const bf16x8*)(ldsB + (brow + j * 16) * 32 + kgrp);
        #pragma unroll
        for (int i = 0; i < 4; ++i)
            #pragma unroll
            for (int j = 0; j < 4; ++j)
                acc[i][j] = __builtin_amdgcn_mfma_f32_16x16x32_bf16(afr[i], bfr[j], acc[i][j], 0, 0, 0);
    }

    // fused epilogue: mask cols >= 1800, rowmax over this block's 128 cols.
    // C/D layout: col = lane&15, row = (lane>>4)*4 + reg  [m89-verified]
    int colBase = nt * 128 + wn * 64 + (lane & 15);
    #pragma unroll
    for (int i = 0; i < 4; ++i) {
        float t[4] = {-__builtin_inff(), -__builtin_inff(), -__builtin_inff(), -__builtin_inff()};
        #pragma unroll
        for (int j = 0; j < 4; ++j) {
            if (colBase + j * 16 < R_DIM) {
                #pragma unroll
                for (int r = 0; r < 4; ++r) t[r] = fmaxf(t[r], acc[i][j][r]);
            }
        }
        #pragma unroll
        for (int m = 1; m <= 8; m <<= 1) {
            #pragma unroll
            for (int r = 0; r < 4; ++r) t[r] = fmaxf(t[r], __shfl_xor(t[r], m));
        }
        if ((lane & 15) == 0) {
            int rb2 = wm * 64 + i * 16 + (lane >> 4) * 4;
            #pragma unroll
            for (int r = 0; r < 4; ++r) red[wn][rb2 + r] = t[r];
        }
    }
    __syncthreads();
    if (tid < 128) {
        float v = fmaxf(red[0][tid], red[1][tid]);
        pmax[((size_t)l * NT + nt) * M_PAD + (size_t)mt * 128 + tid] = v;
    }
}

// ------------------------------------------------------------- K2: combine
__global__ __launch_bounds__(256)
void k_combine(const float* __restrict__ pmax, const float* __restrict__ rnorm,
               float* __restrict__ prm)
{
    int r = blockIdx.x * 256 + threadIdx.x;
    if (r >= M_TOT) return;
    float s = 0.f;
    #pragma unroll
    for (int l = 0; l < L_DIM; ++l) {
        float m = -__builtin_inff();
        #pragma unroll
        for (int t = 0; t < NT; ++t)
            m = fmaxf(m, pmax[((size_t)l * NT + t) * M_PAD + r]);
        s += m * rnorm[l * M_TOT + r];
    }
    prm[r] = (3.0f - s) / 6.0f;   // mean_l (1 - sim)/2
}

// ------------------------------------------------------------- K3: small net
__device__ __forceinline__ float block_sum(float v, volatile float* scratch) {
    #pragma unroll
    for (int m = 32; m; m >>= 1) v += __shfl_xor(v, m);
    int w = threadIdx.x >> 6;
    __syncthreads();
    if ((threadIdx.x & 63) == 0) scratch[w] = v;
    __syncthreads();
    return scratch[0] + scratch[1] + scratch[2] + scratch[3];
}
__device__ __forceinline__ float block_max(float v, volatile float* scratch) {
    #pragma unroll
    for (int m = 32; m; m >>= 1) v = fmaxf(v, __shfl_xor(v, m));
    int w = threadIdx.x >> 6;
    __syncthreads();
    if ((threadIdx.x & 63) == 0) scratch[w] = v;
    __syncthreads();
    return fmaxf(fmaxf(scratch[0], scratch[1]), fmaxf(scratch[2], scratch[3]));
}

__global__ __launch_bounds__(256)
void k_small(const float* __restrict__ ie, const float* __restrict__ te,
             const float* __restrict__ ier,
             const float* __restrict__ a_w1, const float* __restrict__ a_w2,
             const float* __restrict__ r_w1, const float* __restrict__ r_b1,
             const float* __restrict__ r_g2, const float* __restrict__ r_be2,
             const float* __restrict__ r_w2, const float* __restrict__ r_b2,
             const float* __restrict__ r_g3, const float* __restrict__ r_be3,
             const float* __restrict__ r_w3, const float* __restrict__ r_b3,
             const float* __restrict__ h_w1, const float* __restrict__ h_b1,
             const float* __restrict__ h_g2, const float* __restrict__ h_be2,
             const float* __restrict__ h_w2, const float* __restrict__ h_b2,
             const float* __restrict__ h_g3, const float* __restrict__ h_be3,
             const float* __restrict__ h_w3, const float* __restrict__ h_b3,
             const float* __restrict__ prm, float* __restrict__ heat,
             float* __restrict__ out_score)
{
    int b = blockIdx.x, tid = threadIdx.x;
    __shared__ float x[D_DIM];
    __shared__ float h1[160];
    __shared__ float dif[D_DIM];
    __shared__ float z1[128];
    __shared__ float z2[64];
    __shared__ float hol[P_DIM];
    __shared__ float rcp[P_DIM];
    __shared__ float scratch[4];

    for (int i = tid; i < D_DIM; i += 256) x[i] = ie[b * D_DIM + i];
    __syncthreads();

    // text score: softmax(100*nie@te.T)[:,1] = 1/(1+exp(100*inv*(d0-d1)))
    float ss = 0.f, d0 = 0.f, d1 = 0.f;
    for (int i = tid; i < D_DIM; i += 256) {
        float v = x[i];
        ss += v * v;
        d0 += v * te[i];
        d1 += v * te[D_DIM + i];
    }
    float ssum = block_sum(ss, scratch);
    float dd0 = block_sum(d0, scratch);
    float dd1 = block_sum(d1, scratch);
    float tscore = 1.f / (1.f + expf(100.f * rsqrtf(ssum) * (dd0 - dd1)));

    // adapter: relu(relu(x@a_w1.T)@a_w2.T); diff = ier - adapter
    for (int o = tid; o < 160; o += 256) {
        const float* w = a_w1 + (size_t)o * D_DIM;
        float s0 = 0, s1 = 0, s2 = 0, s3 = 0;
        for (int d = 0; d < D_DIM; d += 4) {
            s0 += x[d] * w[d]; s1 += x[d + 1] * w[d + 1];
            s2 += x[d + 2] * w[d + 2]; s3 += x[d + 3] * w[d + 3];
        }
        h1[o] = fmaxf((s0 + s1) + (s2 + s3), 0.f);
    }
    __syncthreads();
    for (int d = tid; d < D_DIM; d += 256) {
        const float* w = a_w2 + (size_t)d * 160;
        float s0 = 0, s1 = 0, s2 = 0, s3 = 0;
        for (int o = 0; o < 160; o += 4) {
            s0 += h1[o] * w[o]; s1 += h1[o + 1] * w[o + 1];
            s2 += h1[o + 2] * w[o + 2]; s3 += h1[o + 3] * w[o + 3];
        }
        dif[d] = ier[d] - fmaxf((s0 + s1) + (s2 + s3), 0.f);
    }
    __syncthreads();

    // r-head
    for (int o = tid; o < 128; o += 256) {
        const float* w = r_w1 + (size_t)o * D_DIM;
        float s0 = 0, s1 = 0, s2 = 0, s3 = 0;
        for (int d = 0; d < D_DIM; d += 4) {
            s0 += dif[d] * w[d]; s1 += dif[d + 1] * w[d + 1];
            s2 += dif[d + 2] * w[d + 2]; s3 += dif[d + 3] * w[d + 3];
        }
        float s = (s0 + s1) + (s2 + s3) + r_b1[o];
        z1[o] = fmaxf(s, 0.f) * (r_g2[o] * BNSCALE) + r_be2[o];
    }
    __syncthreads();
    for (int o = tid; o < 64; o += 256) {
        const float* w = r_w2 + (size_t)o * 128;
        float s = r_b2[o];
        for (int d = 0; d < 128; ++d) s += z1[d] * w[d];
        z2[o] = fmaxf(s, 0.f) * (r_g3[o] * BNSCALE) + r_be3[o];
    }
    __syncthreads();
    float sp = (tid < 64) ? z2[tid] * r_w3[tid] : 0.f;
    float irs = 1.f / (1.f + expf(-(block_sum(sp, scratch) + r_b3[0])));

    // holistic + fg
    float fgp = -__builtin_inff();
    float base = tscore + irs;
    for (int p = tid; p < P_DIM; p += 256) {
        float pv = prm[b * P_DIM + p];
        fgp = fmaxf(fgp, pv);
        float h = base + pv;
        hol[p] = h;
        rcp[p] = 1.f / h;
    }
    float fg = block_max(fgp, scratch);

    // h-head
    for (int o = tid; o < 128; o += 256) {
        const float* w = h_w1 + (size_t)o * P_DIM;
        float s = h_b1[o];
        for (int d = 0; d < P_DIM; ++d) s += hol[d] * w[d];
        z1[o] = fmaxf(s, 0.f) * (h_g2[o] * BNSCALE) + h_be2[o];
    }
    __syncthreads();
    for (int o = tid; o < 64; o += 256) {
        const float* w = h_w2 + (size_t)o * 128;
        float s = h_b2[o];
        for (int d = 0; d < 128; ++d) s += z1[d] * w[d];
        z2[o] = fmaxf(s, 0.f) * (h_g3[o] * BNSCALE) + h_be3[o];
    }
    __syncthreads();
    float sp2 = (tid < 64) ? z2[tid] * h_w3[tid] : 0.f;
    float hl_in = block_sum(sp2, scratch) + h_b3[0];
    if (tid == 0) {
        float hl = 1.f / (1.f + expf(-hl_in));
        out_score[b] = (hl + fg) * 0.5f;
    }

    // heat: count / sum of 1/holistic over covering 2x2 windows
    {
        int r = tid >> 4, c = tid & 15;
        float s = 0.f, cnt = 0.f;
        #pragma unroll
        for (int di = -1; di <= 0; ++di) {
            int i = r + di;
            if (i < 0 || i > 14) continue;
            #pragma unroll
            for (int dj = -1; dj <= 0; ++dj) {
                int j = c + dj;
                if (j < 0 || j > 14) continue;
                s += rcp[i * 15 + j];
                cnt += 1.f;
            }
        }
        heat[b * 256 + tid] = cnt / s;
    }
}

// ------------------------------------------------------------- K4: resize
// jax bilinear resize 16->240 == clamped half-pixel sampling: s=(o-7)/15
__global__ __launch_bounds__(256)
void k_resize(const float* __restrict__ heat, float* __restrict__ outh)
{
    int b = blockIdx.x;
    __shared__ float h[256];
    h[threadIdx.x] = heat[b * 256 + threadIdx.x];
    __syncthreads();
    for (int px = threadIdx.x; px < S_DIM * S_DIM; px += 256) {
        int y = px / S_DIM, xc = px - y * S_DIM;
        float sy = fminf(fmaxf((y - 7) * (1.0f / 15.0f), 0.f), 15.f);
        float sx = fminf(fmaxf((xc - 7) * (1.0f / 15.0f), 0.f), 15.f);
        int y0 = (int)sy, x0 = (int)sx;
        int y1 = min(y0 + 1, 15), x1 = min(x0 + 1, 15);
        float fy = sy - (float)y0, fx = sx - (float)x0;
        float v00 = h[y0 * 16 + x0], v01 = h[y0 * 16 + x1];
        float v10 = h[y1 * 16 + x0], v11 = h[y1 * 16 + x1];
        float v = (1.f - fy) * ((1.f - fx) * v00 + fx * v01)
                + fy * ((1.f - fx) * v10 + fx * v11);
        outh[(size_t)b * (S_DIM * S_DIM) + px] = v;
    }
}

// ---------------------------------------------------------------- launcher
extern "C" void kernel_launch(void* const* d_in, const int* in_sizes, int n_in,
                              void* d_out, int out_size, void* d_ws, size_t ws_size,
                              hipStream_t stream)
{
    (void)in_sizes; (void)n_in; (void)out_size; (void)ws_size;
    // d_in[0] = image: used only for its shape; never read.
    const float* image_embeds = (const float*)d_in[1];
    const float* patch_embeds = (const float*)d_in[2];
    const float* text_embeds  = (const float*)d_in[3];
    const float* ier          = (const float*)d_in[4];
    const float* per          = (const float*)d_in[5];
    const float* a_w1 = (const float*)d_in[6];
    const float* a_w2 = (const float*)d_in[7];
    const float* r_w1 = (const float*)d_in[8];
    const float* r_b1 = (const float*)d_in[9];
    const float* r_g2 = (const float*)d_in[10];
    const float* r_be2 = (const float*)d_in[11];
    const float* r_w2 = (const float*)d_in[12];
    const float* r_b2 = (const float*)d_in[13];
    const float* r_g3 = (const float*)d_in[14];
    const float* r_be3 = (const float*)d_in[15];
    const float* r_w3 = (const float*)d_in[16];
    const float* r_b3 = (const float*)d_in[17];
    const float* h_w1 = (const float*)d_in[18];
    const float* h_b1 = (const float*)d_in[19];
    const float* h_g2 = (const float*)d_in[20];
    const float* h_be2 = (const float*)d_in[21];
    const float* h_w2 = (const float*)d_in[22];
    const float* h_b2 = (const float*)d_in[23];
    const float* h_g3 = (const float*)d_in[24];
    const float* h_be3 = (const float*)d_in[25];
    const float* h_w3 = (const float*)d_in[26];
    const float* h_b3 = (const float*)d_in[27];

    char* ws = (char*)d_ws;
    size_t off = 0;
    auto take = [&](size_t bytes) -> void* {
        void* p = ws + off;
        off += (bytes + 255) & ~(size_t)255;
        return p;
    };
    float* rnorm = (float*)take((size_t)L_DIM * M_TOT * 4);        // 173 KB
    float* pmax  = (float*)take((size_t)L_DIM * NT * M_PAD * 4);   // 2.6 MB
    float* prm   = (float*)take((size_t)M_TOT * 4);                // 58 KB
    float* heat  = (float*)take((size_t)B_DIM * 256 * 4);          // 64 KB

    float* out_f = (float*)d_out;  // [64] final_score || [64*240*240] hmap, f32

    k_norms<<<dim3(L_DIM * M_TOT / 4), dim3(256), 0, stream>>>(patch_embeds, rnorm);
    k_gemm_max<<<dim3(L_DIM * MT * NT), dim3(256), 0, stream>>>(patch_embeds, per, pmax);
    k_combine<<<dim3((M_TOT + 255) / 256), dim3(256), 0, stream>>>(pmax, rnorm, prm);
    k_small<<<dim3(B_DIM), dim3(256), 0, stream>>>(image_embeds, text_embeds, ier,
        a_w1, a_w2, r_w1, r_b1, r_g2, r_be2, r_w2, r_b2, r_g3, r_be3, r_w3, r_b3,
        h_w1, h_b1, h_g2, h_be2, h_w2, h_b2, h_g3, h_be3, h_w3, h_b3,
        prm, heat, out_f);
    k_resize<<<dim3(B_DIM), dim3(256), 0, stream>>>(heat, out_f + B_DIM);
}

// Round 4
// 233.076 us; speedup vs baseline: 2.9730x; 2.9730x over previous
//
#include <hip/hip_runtime.h>
#include <stdint.h>
#include <math.h>

#define L_DIM 3
#define B_DIM 64
#define P_DIM 225
#define D_DIM 640
#define R_DIM 1800
#define S_DIM 240
#define M_TOT (B_DIM * P_DIM)   /* 14400 */
#define M_PAD 14464             /* 113*128 */
#define N_PAD 1920              /* 15*128 */
#define MT 113
#define NT 15
#define KSTEPS (D_DIM / 32)     /* 20 */
#define BNSCALE 0.99999500003749981f  /* 1/sqrt(1+1e-5) */

typedef __bf16 bf16x8 __attribute__((ext_vector_type(8)));
typedef __bf16 bf16x4 __attribute__((ext_vector_type(4)));
typedef float f32x4 __attribute__((ext_vector_type(4)));
typedef float fvec4 __attribute__((ext_vector_type(4)));

__device__ __forceinline__ unsigned short f2bf(float f) {
    union { float f; unsigned u; } v; v.f = f;
    unsigned u = v.u;
    unsigned r = (u + 0x7FFFu + ((u >> 16) & 1u)) >> 16;   // RNE
    return (unsigned short)r;
}

// ---------------------------------------------------------------- K0: convert
// one wave per 640-elem row; A rows also compute rsqrt(sum(x^2)) (fused norms).
__global__ __launch_bounds__(256)
void k_convert(const float* __restrict__ pe, const float* __restrict__ per,
               unsigned short* __restrict__ abf, unsigned short* __restrict__ rbf,
               float* __restrict__ rnorm)
{
    const int AROWS = L_DIM * M_PAD;            // 43392
    int wid = (blockIdx.x * 256 + threadIdx.x) >> 6;
    int lane = threadIdx.x & 63;
    if (wid < AROWS) {
        int l = wid / M_PAD, r = wid - l * M_PAD;
        unsigned* dst = (unsigned*)(abf + (size_t)wid * D_DIM);
        if (r < M_TOT) {
            const float* src = pe + ((size_t)l * M_TOT + r) * D_DIM;
            float ss = 0.f;
            #pragma unroll
            for (int it = 0; it < 5; ++it) {
                float2 v = *(const float2*)(src + it * 128 + lane * 2);
                ss += v.x * v.x + v.y * v.y;
                dst[it * 64 + lane] = (unsigned)f2bf(v.x) | ((unsigned)f2bf(v.y) << 16);
            }
            #pragma unroll
            for (int m = 32; m; m >>= 1) ss += __shfl_xor(ss, m);
            if (lane == 0) rnorm[l * M_TOT + r] = rsqrtf(ss);
        } else {                                 // zero pad rows
            #pragma unroll
            for (int it = 0; it < 5; ++it) dst[it * 64 + lane] = 0u;
        }
    } else {
        int w2 = wid - AROWS;
        int l = w2 / N_PAD, r = w2 - l * N_PAD;
        unsigned* dst = (unsigned*)(rbf + (size_t)w2 * D_DIM);
        if (r < R_DIM) {
            const float* src = per + ((size_t)l * R_DIM + r) * D_DIM;
            #pragma unroll
            for (int it = 0; it < 5; ++it) {
                float2 v = *(const float2*)(src + it * 128 + lane * 2);
                dst[it * 64 + lane] = (unsigned)f2bf(v.x) | ((unsigned)f2bf(v.y) << 16);
            }
        } else {
            #pragma unroll
            for (int it = 0; it < 5; ++it) dst[it * 64 + lane] = 0u;
        }
    }
}

// ---------------------------------------- K1 (main): bf16 GEMM + fused rowmax
// m97 structure: 128x128 tile, 4 waves (2x2 of 64x64), BK=32,
// global_load_lds width=16, mfma_f32_16x16x32_bf16.
__global__ __launch_bounds__(256)
void k_gemm_max_bf16(const unsigned short* __restrict__ abf,
                     const unsigned short* __restrict__ rbf,
                     float* __restrict__ pmax)
{
    __shared__ alignas(16) unsigned short ldsA[128 * 32];
    __shared__ alignas(16) unsigned short ldsB[128 * 32];
    __shared__ float red[2][128];

    int bid = blockIdx.x;
    int l = bid / (MT * NT);
    int rem = bid - l * (MT * NT);
    int mt = rem / NT;
    int nt = rem - mt * NT;

    int tid = threadIdx.x;
    int wave = tid >> 6, lane = tid & 63;
    int wm = wave >> 1, wn = wave & 1;

    const unsigned short* gA = abf + ((size_t)l * M_PAD + (size_t)mt * 128) * D_DIM;
    const unsigned short* gB = rbf + ((size_t)l * N_PAD + (size_t)nt * 128) * D_DIM;

    // staging: wave w fills 1KiB chunks {2w,2w+1} of A and B.
    // LDS dest = wave-uniform base + lane*16B; source row = c*16 + lane/4, seg = lane&3.
    int c0 = wave * 2, c1 = wave * 2 + 1;
    int srow0 = c0 * 16 + (lane >> 2);
    int srow1 = c1 * 16 + (lane >> 2);
    int scol = (lane & 3) * 8;
    const unsigned short* pa0 = gA + (size_t)srow0 * D_DIM + scol;
    const unsigned short* pa1 = gA + (size_t)srow1 * D_DIM + scol;
    const unsigned short* pb0 = gB + (size_t)srow0 * D_DIM + scol;
    const unsigned short* pb1 = gB + (size_t)srow1 * D_DIM + scol;

    f32x4 acc[4][4];
    #pragma unroll
    for (int i = 0; i < 4; ++i)
        #pragma unroll
        for (int j = 0; j < 4; ++j)
            acc[i][j] = f32x4{0.f, 0.f, 0.f, 0.f};

    int arow = wm * 64 + (lane & 15);
    int brow = wn * 64 + (lane & 15);
    int kgrp = (lane >> 4) * 8;

    for (int kk = 0; kk < D_DIM; kk += 32) {
        __builtin_amdgcn_global_load_lds(
            (const __attribute__((address_space(1))) void*)(pa0 + kk),
            (__attribute__((address_space(3))) void*)(ldsA + c0 * 512), 16, 0, 0);
        __builtin_amdgcn_global_load_lds(
            (const __attribute__((address_space(1))) void*)(pa1 + kk),
            (__attribute__((address_space(3))) void*)(ldsA + c1 * 512), 16, 0, 0);
        __builtin_amdgcn_global_load_lds(
            (const __attribute__((address_space(1))) void*)(pb0 + kk),
            (__attribute__((address_space(3))) void*)(ldsB + c0 * 512), 16, 0, 0);
        __builtin_amdgcn_global_load_lds(
            (const __attribute__((address_space(1))) void*)(pb1 + kk),
            (__attribute__((address_space(3))) void*)(ldsB + c1 * 512), 16, 0, 0);
        __syncthreads();

        bf16x8 afr[4], bfr[4];
        #pragma unroll
        for (int i = 0; i < 4; ++i)
            afr[i] = *(const bf16x8*)(ldsA + (arow + i * 16) * 32 + kgrp);
        #pragma unroll
        for (int j = 0; j < 4; ++j)
            bfr[j] = *(const bf16x8*)(ldsB + (brow + j * 16) * 32 + kgrp);
        #pragma unroll
        for (int i = 0; i < 4; ++i)
            #pragma unroll
            for (int j = 0; j < 4; ++j)
                acc[i][j] = __builtin_amdgcn_mfma_f32_16x16x32_bf16(afr[i], bfr[j], acc[i][j], 0, 0, 0);
        __syncthreads();
    }

    // fused epilogue: mask cols >= 1800, rowmax over this block's 128 cols.
    // C/D layout: col = lane&15, row = (lane>>4)*4 + reg  [m89-verified]
    int colBase = nt * 128 + wn * 64 + (lane & 15);
    #pragma unroll
    for (int i = 0; i < 4; ++i) {
        float t[4] = {-__builtin_inff(), -__builtin_inff(), -__builtin_inff(), -__builtin_inff()};
        #pragma unroll
        for (int j = 0; j < 4; ++j) {
            if (colBase + j * 16 < R_DIM) {
                #pragma unroll
                for (int r = 0; r < 4; ++r) t[r] = fmaxf(t[r], acc[i][j][r]);
            }
        }
        #pragma unroll
        for (int m = 1; m <= 8; m <<= 1) {
            #pragma unroll
            for (int r = 0; r < 4; ++r) t[r] = fmaxf(t[r], __shfl_xor(t[r], m));
        }
        if ((lane & 15) == 0) {
            int rb2 = wm * 64 + i * 16 + (lane >> 4) * 4;
            #pragma unroll
            for (int r = 0; r < 4; ++r) red[wn][rb2 + r] = t[r];
        }
    }
    __syncthreads();
    if (tid < 128) {
        float v = fmaxf(red[0][tid], red[1][tid]);
        pmax[((size_t)l * NT + nt) * M_PAD + (size_t)mt * 128 + tid] = v;
    }
}

// --------------------------------------- fallback path (round-3, proven) ----
__global__ __launch_bounds__(256)
void k_norms(const float* __restrict__ pe, float* __restrict__ rnorm)
{
    int wid = (blockIdx.x * 256 + threadIdx.x) >> 6;
    int lane = threadIdx.x & 63;
    const float* src = pe + (size_t)wid * D_DIM;
    float ss = 0.f;
    #pragma unroll
    for (int it = 0; it < 5; ++it) {
        float2 v = *(const float2*)(src + it * 128 + lane * 2);
        ss += v.x * v.x + v.y * v.y;
    }
    #pragma unroll
    for (int m = 32; m; m >>= 1) ss += __shfl_xor(ss, m);
    if (lane == 0) rnorm[wid] = rsqrtf(ss);
}

__global__ __launch_bounds__(256)
void k_gemm_max_f32(const float* __restrict__ pe, const float* __restrict__ per,
                    float* __restrict__ pmax)
{
    __shared__ alignas(16) unsigned short ldsA[128 * 32];
    __shared__ alignas(16) unsigned short ldsB[128 * 32];
    __shared__ float red[2][128];

    int bid = blockIdx.x;
    int l = bid / (MT * NT);
    int rem = bid - l * (MT * NT);
    int mt = rem / NT;
    int nt = rem - mt * NT;

    int tid = threadIdx.x;
    int wave = tid >> 6, lane = tid & 63;
    int wm = wave >> 1, wn = wave & 1;

    const float* gA = pe + (size_t)l * M_TOT * D_DIM;
    const float* gB = per + (size_t)l * R_DIM * D_DIM;

    const float* pa[4]; const float* pb[4];
    bool va[4], vb[4];
    int lofs[4];
    #pragma unroll
    for (int i = 0; i < 4; ++i) {
        int f = i * 256 + tid;
        int row = f >> 3, seg = f & 7;
        lofs[i] = row * 32 + seg * 4;
        int gar = mt * 128 + row;
        int gbr = nt * 128 + row;
        va[i] = gar < M_TOT;
        vb[i] = gbr < R_DIM;
        pa[i] = gA + (size_t)(va[i] ? gar : 0) * D_DIM + seg * 4;
        pb[i] = gB + (size_t)(vb[i] ? gbr : 0) * D_DIM + seg * 4;
    }

    f32x4 acc[4][4];
    #pragma unroll
    for (int i = 0; i < 4; ++i)
        #pragma unroll
        for (int j = 0; j < 4; ++j)
            acc[i][j] = f32x4{0.f, 0.f, 0.f, 0.f};

    int arow = wm * 64 + (lane & 15);
    int brow = wn * 64 + (lane & 15);
    int kgrp = (lane >> 4) * 8;

    fvec4 ra[4], rb[4];
    const fvec4 z4 = fvec4{0.f, 0.f, 0.f, 0.f};
    #pragma unroll
    for (int i = 0; i < 4; ++i) {
        ra[i] = va[i] ? *(const fvec4*)(pa[i]) : z4;
        rb[i] = vb[i] ? *(const fvec4*)(pb[i]) : z4;
    }

    for (int ks = 0; ks < KSTEPS; ++ks) {
        __syncthreads();
        #pragma unroll
        for (int i = 0; i < 4; ++i) {
            *(bf16x4*)(ldsA + lofs[i]) = __builtin_convertvector(ra[i], bf16x4);
            *(bf16x4*)(ldsB + lofs[i]) = __builtin_convertvector(rb[i], bf16x4);
        }
        __syncthreads();
        if (ks + 1 < KSTEPS) {
            int off = (ks + 1) * 32;
            #pragma unroll
            for (int i = 0; i < 4; ++i) {
                ra[i] = va[i] ? *(const fvec4*)(pa[i] + off) : z4;
                rb[i] = vb[i] ? *(const fvec4*)(pb[i] + off) : z4;
            }
        }
        bf16x8 afr[4], bfr[4];
        #pragma unroll
        for (int i = 0; i < 4; ++i)
            afr[i] = *(const bf16x8*)(ldsA + (arow + i * 16) * 32 + kgrp);
        #pragma unroll
        for (int j = 0; j < 4; ++j)
            bfr[j] = *(const bf16x8*)(ldsB + (brow + j * 16) * 32 + kgrp);
        #pragma unroll
        for (int i = 0; i < 4; ++i)
            #pragma unroll
            for (int j = 0; j < 4; ++j)
                acc[i][j] = __builtin_amdgcn_mfma_f32_16x16x32_bf16(afr[i], bfr[j], acc[i][j], 0, 0, 0);
    }

    int colBase = nt * 128 + wn * 64 + (lane & 15);
    #pragma unroll
    for (int i = 0; i < 4; ++i) {
        float t[4] = {-__builtin_inff(), -__builtin_inff(), -__builtin_inff(), -__builtin_inff()};
        #pragma unroll
        for (int j = 0; j < 4; ++j) {
            if (colBase + j * 16 < R_DIM) {
                #pragma unroll
                for (int r = 0; r < 4; ++r) t[r] = fmaxf(t[r], acc[i][j][r]);
            }
        }
        #pragma unroll
        for (int m = 1; m <= 8; m <<= 1) {
            #pragma unroll
            for (int r = 0; r < 4; ++r) t[r] = fmaxf(t[r], __shfl_xor(t[r], m));
        }
        if ((lane & 15) == 0) {
            int rb2 = wm * 64 + i * 16 + (lane >> 4) * 4;
            #pragma unroll
            for (int r = 0; r < 4; ++r) red[wn][rb2 + r] = t[r];
        }
    }
    __syncthreads();
    if (tid < 128) {
        float v = fmaxf(red[0][tid], red[1][tid]);
        pmax[((size_t)l * NT + nt) * M_PAD + (size_t)mt * 128 + tid] = v;
    }
}

// ------------------------------------------------------------- K2: combine
__global__ __launch_bounds__(256)
void k_combine(const float* __restrict__ pmax, const float* __restrict__ rnorm,
               float* __restrict__ prm)
{
    int r = blockIdx.x * 256 + threadIdx.x;
    if (r >= M_TOT) return;
    float s = 0.f;
    #pragma unroll
    for (int l = 0; l < L_DIM; ++l) {
        float m = -__builtin_inff();
        #pragma unroll
        for (int t = 0; t < NT; ++t)
            m = fmaxf(m, pmax[((size_t)l * NT + t) * M_PAD + r]);
        s += m * rnorm[l * M_TOT + r];
    }
    prm[r] = (3.0f - s) / 6.0f;   // mean_l (1 - sim)/2
}

// ------------------------------------------------------------- K3: small net
__device__ __forceinline__ float block_sum(float v, volatile float* scratch) {
    #pragma unroll
    for (int m = 32; m; m >>= 1) v += __shfl_xor(v, m);
    int w = threadIdx.x >> 6;
    __syncthreads();
    if ((threadIdx.x & 63) == 0) scratch[w] = v;
    __syncthreads();
    return scratch[0] + scratch[1] + scratch[2] + scratch[3];
}
__device__ __forceinline__ float block_max(float v, volatile float* scratch) {
    #pragma unroll
    for (int m = 32; m; m >>= 1) v = fmaxf(v, __shfl_xor(v, m));
    int w = threadIdx.x >> 6;
    __syncthreads();
    if ((threadIdx.x & 63) == 0) scratch[w] = v;
    __syncthreads();
    return fmaxf(fmaxf(scratch[0], scratch[1]), fmaxf(scratch[2], scratch[3]));
}

__global__ __launch_bounds__(256)
void k_small(const float* __restrict__ ie, const float* __restrict__ te,
             const float* __restrict__ ier,
             const float* __restrict__ a_w1, const float* __restrict__ a_w2,
             const float* __restrict__ r_w1, const float* __restrict__ r_b1,
             const float* __restrict__ r_g2, const float* __restrict__ r_be2,
             const float* __restrict__ r_w2, const float* __restrict__ r_b2,
             const float* __restrict__ r_g3, const float* __restrict__ r_be3,
             const float* __restrict__ r_w3, const float* __restrict__ r_b3,
             const float* __restrict__ h_w1, const float* __restrict__ h_b1,
             const float* __restrict__ h_g2, const float* __restrict__ h_be2,
             const float* __restrict__ h_w2, const float* __restrict__ h_b2,
             const float* __restrict__ h_g3, const float* __restrict__ h_be3,
             const float* __restrict__ h_w3, const float* __restrict__ h_b3,
             const float* __restrict__ prm, float* __restrict__ heat,
             float* __restrict__ out_score)
{
    int b = blockIdx.x, tid = threadIdx.x;
    __shared__ float x[D_DIM];
    __shared__ float h1[160];
    __shared__ float dif[D_DIM];
    __shared__ float z1[128];
    __shared__ float z2[64];
    __shared__ float hol[P_DIM];
    __shared__ float rcp[P_DIM];
    __shared__ float scratch[4];

    for (int i = tid; i < D_DIM; i += 256) x[i] = ie[b * D_DIM + i];
    __syncthreads();

    float ss = 0.f, d0 = 0.f, d1 = 0.f;
    for (int i = tid; i < D_DIM; i += 256) {
        float v = x[i];
        ss += v * v;
        d0 += v * te[i];
        d1 += v * te[D_DIM + i];
    }
    float ssum = block_sum(ss, scratch);
    float dd0 = block_sum(d0, scratch);
    float dd1 = block_sum(d1, scratch);
    float tscore = 1.f / (1.f + expf(100.f * rsqrtf(ssum) * (dd0 - dd1)));

    for (int o = tid; o < 160; o += 256) {
        const float* w = a_w1 + (size_t)o * D_DIM;
        float s0 = 0, s1 = 0, s2 = 0, s3 = 0;
        for (int d = 0; d < D_DIM; d += 4) {
            s0 += x[d] * w[d]; s1 += x[d + 1] * w[d + 1];
            s2 += x[d + 2] * w[d + 2]; s3 += x[d + 3] * w[d + 3];
        }
        h1[o] = fmaxf((s0 + s1) + (s2 + s3), 0.f);
    }
    __syncthreads();
    for (int d = tid; d < D_DIM; d += 256) {
        const float* w = a_w2 + (size_t)d * 160;
        float s0 = 0, s1 = 0, s2 = 0, s3 = 0;
        for (int o = 0; o < 160; o += 4) {
            s0 += h1[o] * w[o]; s1 += h1[o + 1] * w[o + 1];
            s2 += h1[o + 2] * w[o + 2]; s3 += h1[o + 3] * w[o + 3];
        }
        dif[d] = ier[d] - fmaxf((s0 + s1) + (s2 + s3), 0.f);
    }
    __syncthreads();

    for (int o = tid; o < 128; o += 256) {
        const float* w = r_w1 + (size_t)o * D_DIM;
        float s0 = 0, s1 = 0, s2 = 0, s3 = 0;
        for (int d = 0; d < D_DIM; d += 4) {
            s0 += dif[d] * w[d]; s1 += dif[d + 1] * w[d + 1];
            s2 += dif[d + 2] * w[d + 2]; s3 += dif[d + 3] * w[d + 3];
        }
        float s = (s0 + s1) + (s2 + s3) + r_b1[o];
        z1[o] = fmaxf(s, 0.f) * (r_g2[o] * BNSCALE) + r_be2[o];
    }
    __syncthreads();
    for (int o = tid; o < 64; o += 256) {
        const float* w = r_w2 + (size_t)o * 128;
        float s = r_b2[o];
        for (int d = 0; d < 128; ++d) s += z1[d] * w[d];
        z2[o] = fmaxf(s, 0.f) * (r_g3[o] * BNSCALE) + r_be3[o];
    }
    __syncthreads();
    float sp = (tid < 64) ? z2[tid] * r_w3[tid] : 0.f;
    float irs = 1.f / (1.f + expf(-(block_sum(sp, scratch) + r_b3[0])));

    float fgp = -__builtin_inff();
    float base = tscore + irs;
    for (int p = tid; p < P_DIM; p += 256) {
        float pv = prm[b * P_DIM + p];
        fgp = fmaxf(fgp, pv);
        float h = base + pv;
        hol[p] = h;
        rcp[p] = 1.f / h;
    }
    float fg = block_max(fgp, scratch);

    for (int o = tid; o < 128; o += 256) {
        const float* w = h_w1 + (size_t)o * P_DIM;
        float s = h_b1[o];
        for (int d = 0; d < P_DIM; ++d) s += hol[d] * w[d];
        z1[o] = fmaxf(s, 0.f) * (h_g2[o] * BNSCALE) + h_be2[o];
    }
    __syncthreads();
    for (int o = tid; o < 64; o += 256) {
        const float* w = h_w2 + (size_t)o * 128;
        float s = h_b2[o];
        for (int d = 0; d < 128; ++d) s += z1[d] * w[d];
        z2[o] = fmaxf(s, 0.f) * (h_g3[o] * BNSCALE) + h_be3[o];
    }
    __syncthreads();
    float sp2 = (tid < 64) ? z2[tid] * h_w3[tid] : 0.f;
    float hl_in = block_sum(sp2, scratch) + h_b3[0];
    if (tid == 0) {
        float hl = 1.f / (1.f + expf(-hl_in));
        out_score[b] = (hl + fg) * 0.5f;
    }

    {
        int r = tid >> 4, c = tid & 15;
        float s = 0.f, cnt = 0.f;
        #pragma unroll
        for (int di = -1; di <= 0; ++di) {
            int i = r + di;
            if (i < 0 || i > 14) continue;
            #pragma unroll
            for (int dj = -1; dj <= 0; ++dj) {
                int j = c + dj;
                if (j < 0 || j > 14) continue;
                s += rcp[i * 15 + j];
                cnt += 1.f;
            }
        }
        heat[b * 256 + tid] = cnt / s;
    }
}

// ------------------------------------------------------------- K4: resize
// jax bilinear 16->240 == clamped half-pixel sampling: s=(o-7)/15.
// grid = 64*8 blocks; block handles 30 output rows of one image.
__global__ __launch_bounds__(256)
void k_resize(const float* __restrict__ heat, float* __restrict__ outh)
{
    int b = blockIdx.x >> 3, sub = blockIdx.x & 7;
    __shared__ float h[256];
    if (threadIdx.x < 256) h[threadIdx.x] = heat[b * 256 + threadIdx.x];
    __syncthreads();
    int base = sub * 30 * S_DIM;
    for (int q = threadIdx.x; q < 30 * S_DIM; q += 256) {
        int px = base + q;
        int y = px / S_DIM, xc = px - y * S_DIM;
        float sy = fminf(fmaxf((y - 7) * (1.0f / 15.0f), 0.f), 15.f);
        float sx = fminf(fmaxf((xc - 7) * (1.0f / 15.0f), 0.f), 15.f);
        int y0 = (int)sy, x0 = (int)sx;
        int y1 = min(y0 + 1, 15), x1 = min(x0 + 1, 15);
        float fy = sy - (float)y0, fx = sx - (float)x0;
        float v00 = h[y0 * 16 + x0], v01 = h[y0 * 16 + x1];
        float v10 = h[y1 * 16 + x0], v11 = h[y1 * 16 + x1];
        float v = (1.f - fy) * ((1.f - fx) * v00 + fx * v01)
                + fy * ((1.f - fx) * v10 + fx * v11);
        outh[(size_t)b * (S_DIM * S_DIM) + px] = v;
    }
}

// ---------------------------------------------------------------- launcher
extern "C" void kernel_launch(void* const* d_in, const int* in_sizes, int n_in,
                              void* d_out, int out_size, void* d_ws, size_t ws_size,
                              hipStream_t stream)
{
    (void)in_sizes; (void)n_in; (void)out_size;
    const float* image_embeds = (const float*)d_in[1];
    const float* patch_embeds = (const float*)d_in[2];
    const float* text_embeds  = (const float*)d_in[3];
    const float* ier          = (const float*)d_in[4];
    const float* per          = (const float*)d_in[5];
    const float* a_w1 = (const float*)d_in[6];
    const float* a_w2 = (const float*)d_in[7];
    const float* r_w1 = (const float*)d_in[8];
    const float* r_b1 = (const float*)d_in[9];
    const float* r_g2 = (const float*)d_in[10];
    const float* r_be2 = (const float*)d_in[11];
    const float* r_w2 = (const float*)d_in[12];
    const float* r_b2 = (const float*)d_in[13];
    const float* r_g3 = (const float*)d_in[14];
    const float* r_be3 = (const float*)d_in[15];
    const float* r_w3 = (const float*)d_in[16];
    const float* r_b3 = (const float*)d_in[17];
    const float* h_w1 = (const float*)d_in[18];
    const float* h_b1 = (const float*)d_in[19];
    const float* h_g2 = (const float*)d_in[20];
    const float* h_be2 = (const float*)d_in[21];
    const float* h_w2 = (const float*)d_in[22];
    const float* h_b2 = (const float*)d_in[23];
    const float* h_g3 = (const float*)d_in[24];
    const float* h_be3 = (const float*)d_in[25];
    const float* h_w3 = (const float*)d_in[26];
    const float* h_b3 = (const float*)d_in[27];

    char* ws = (char*)d_ws;
    size_t off = 0;
    auto take = [&](size_t bytes) -> void* {
        void* p = ws + off;
        off += (bytes + 255) & ~(size_t)255;
        return p;
    };
    // small buffers first (both paths use them)
    float* rnorm = (float*)take((size_t)L_DIM * M_TOT * 4);        // 173 KB
    float* pmax  = (float*)take((size_t)L_DIM * NT * M_PAD * 4);   // 2.6 MB
    float* prm   = (float*)take((size_t)M_TOT * 4);                // 58 KB
    float* heat  = (float*)take((size_t)B_DIM * 256 * 4);          // 64 KB
    // bf16 staging buffers (main path only)
    size_t off_small = off;
    unsigned short* abf = (unsigned short*)take((size_t)L_DIM * M_PAD * D_DIM * 2); // 55.6 MB
    unsigned short* rbf = (unsigned short*)take((size_t)L_DIM * N_PAD * D_DIM * 2); //  7.4 MB
    bool use_bf16 = (off <= ws_size);
    (void)off_small;

    float* out_f = (float*)d_out;  // [64] final_score || [64*240*240] hmap, f32

    if (use_bf16) {
        k_convert<<<dim3((L_DIM * M_PAD + L_DIM * N_PAD) / 4), dim3(256), 0, stream>>>(
            patch_embeds, per, abf, rbf, rnorm);
        k_gemm_max_bf16<<<dim3(L_DIM * MT * NT), dim3(256), 0, stream>>>(abf, rbf, pmax);
    } else {
        k_norms<<<dim3(L_DIM * M_TOT / 4), dim3(256), 0, stream>>>(patch_embeds, rnorm);
        k_gemm_max_f32<<<dim3(L_DIM * MT * NT), dim3(256), 0, stream>>>(patch_embeds, per, pmax);
    }
    k_combine<<<dim3((M_TOT + 255) / 256), dim3(256), 0, stream>>>(pmax, rnorm, prm);
    k_small<<<dim3(B_DIM), dim3(256), 0, stream>>>(image_embeds, text_embeds, ier,
        a_w1, a_w2, r_w1, r_b1, r_g2, r_be2, r_w2, r_b2, r_g3, r_be3, r_w3, r_b3,
        h_w1, h_b1, h_g2, h_be2, h_w2, h_b2, h_g3, h_be3, h_w3, h_b3,
        prm, heat, out_f);
    k_resize<<<dim3(B_DIM * 8), dim3(256), 0, stream>>>(heat, out_f + B_DIM);
}

// Round 5
// 207.757 us; speedup vs baseline: 3.3353x; 1.1219x over previous
//
#include <hip/hip_runtime.h>
#include <stdint.h>
#include <math.h>

#define L_DIM 3
#define B_DIM 64
#define P_DIM 225
#define D_DIM 640
#define R_DIM 1800
#define S_DIM 240
#define M_TOT 14400
#define M_PAD 14592             /* 57*256 */
#define N_PAD 2048              /* 8*256 */
#define MT 57
#define NT 8
#define KT 10                   /* 640/64 */
#define BNSCALE 0.99999500003749981f  /* 1/sqrt(1+1e-5) */

typedef __bf16 bf16x8 __attribute__((ext_vector_type(8)));
typedef float f32x4 __attribute__((ext_vector_type(4)));

__device__ __forceinline__ unsigned short f2bf(float f) {
    union { float f; unsigned u; } v; v.f = f;
    unsigned u = v.u;
    unsigned r = (u + 0x7FFFu + ((u >> 16) & 1u)) >> 16;   // RNE
    return (unsigned short)r;
}

// ---------------------------------------------------------------- K0: convert
// one wave per 640-elem row; A rows also compute rsqrt(sum(x^2)) (fused norms).
__global__ __launch_bounds__(256)
void k_convert(const float* __restrict__ pe, const float* __restrict__ per,
               unsigned short* __restrict__ abf, unsigned short* __restrict__ rbf,
               float* __restrict__ rnorm)
{
    const int AROWS = L_DIM * M_PAD;            // 43776
    int wid = (blockIdx.x * 256 + threadIdx.x) >> 6;
    int lane = threadIdx.x & 63;
    if (wid < AROWS) {
        int l = wid / M_PAD, r = wid - l * M_PAD;
        unsigned* dst = (unsigned*)(abf + (size_t)wid * D_DIM);
        if (r < M_TOT) {
            const float* src = pe + ((size_t)l * M_TOT + r) * D_DIM;
            float ss = 0.f;
            #pragma unroll
            for (int it = 0; it < 5; ++it) {
                float2 v = *(const float2*)(src + it * 128 + lane * 2);
                ss += v.x * v.x + v.y * v.y;
                dst[it * 64 + lane] = (unsigned)f2bf(v.x) | ((unsigned)f2bf(v.y) << 16);
            }
            #pragma unroll
            for (int m = 32; m; m >>= 1) ss += __shfl_xor(ss, m);
            if (lane == 0) rnorm[l * M_TOT + r] = rsqrtf(ss);
        } else {                                 // zero pad rows
            #pragma unroll
            for (int it = 0; it < 5; ++it) dst[it * 64 + lane] = 0u;
        }
    } else {
        int w2 = wid - AROWS;
        int l = w2 / N_PAD, r = w2 - l * N_PAD;
        unsigned* dst = (unsigned*)(rbf + (size_t)w2 * D_DIM);
        if (r < R_DIM) {
            const float* src = per + ((size_t)l * R_DIM + r) * D_DIM;
            #pragma unroll
            for (int it = 0; it < 5; ++it) {
                float2 v = *(const float2*)(src + it * 128 + lane * 2);
                dst[it * 64 + lane] = (unsigned)f2bf(v.x) | ((unsigned)f2bf(v.y) << 16);
            }
        } else {
            #pragma unroll
            for (int it = 0; it < 5; ++it) dst[it * 64 + lane] = 0u;
        }
    }
}

// ----------------------------------- K1: 256^2 4-phase bf16 GEMM + fused rowmax
// T1 XCD swizzle + T2 LDS XOR swizzle + T3/T4 counted-vmcnt phase pipeline + T5.
#define MFMA(A, B, C) __builtin_amdgcn_mfma_f32_16x16x32_bf16((A), (B), (C), 0, 0, 0)
#define GLL(SRC, DSTOFF)                                                     \
    __builtin_amdgcn_global_load_lds(                                        \
        (const __attribute__((address_space(1))) void*)(SRC),               \
        (__attribute__((address_space(3))) void*)(lds + (DSTOFF)), 16, 0, 0)

#define PHASE_TAIL(NJB, STG0, STG1, VMSTR)                                   \
    {                                                                        \
        bf16x8 b00 = *(const bf16x8*)(lds + bB + (brow0 + (NJB) * 16) * 64 + sw0);     \
        bf16x8 b01 = *(const bf16x8*)(lds + bB + (brow0 + (NJB) * 16) * 64 + sw1);     \
        bf16x8 b10 = *(const bf16x8*)(lds + bB + (brow0 + (NJB + 1) * 16) * 64 + sw0); \
        bf16x8 b11 = *(const bf16x8*)(lds + bB + (brow0 + (NJB + 1) * 16) * 64 + sw1); \
        STG0; STG1;                                                          \
        asm volatile("s_waitcnt " VMSTR ::: "memory");                       \
        __builtin_amdgcn_s_barrier();                                        \
        __builtin_amdgcn_s_setprio(1);                                       \
        _Pragma("unroll")                                                    \
        for (int mi = 0; mi < 4; ++mi) {                                     \
            acc[mi][NJB]     = MFMA(a[mi][0], b00, acc[mi][NJB]);            \
            acc[mi][NJB]     = MFMA(a[mi][1], b01, acc[mi][NJB]);            \
            acc[mi][NJB + 1] = MFMA(a[mi][0], b10, acc[mi][NJB + 1]);        \
            acc[mi][NJB + 1] = MFMA(a[mi][1], b11, acc[mi][NJB + 1]);        \
        }                                                                    \
        __builtin_amdgcn_s_setprio(0);                                       \
        __builtin_amdgcn_s_barrier();                                        \
    }

__global__ __launch_bounds__(512, 2)
void k_gemm_max(const unsigned short* __restrict__ abf,
                const unsigned short* __restrict__ rbf,
                float* __restrict__ pmax)
{
    __shared__ unsigned short lds[65536];   // A: [0,32768) 2 bufs; B: [32768,65536)
    __shared__ float red[2][256];

    // XCD-chunked bijective swizzle: 1368 blocks = 8 XCDs * 171
    int bid = blockIdx.x;
    int v = (bid & 7) * 171 + (bid >> 3);
    int l = v / (MT * NT);
    int rem = v - l * (MT * NT);
    int mt = rem >> 3;
    int nt = rem & 7;

    int tid = threadIdx.x;
    int wid = tid >> 6, lane = tid & 63;
    int wm = wid >> 1;                      // 0..3 -> rows wm*64..+64
    int wn = wid & 1;                       // 0..1 -> cols wn*128..+128
    int lane15 = lane & 15, lg = lane >> 4;
    int sA = lane15 & 7;                    // row&7 for all frag rows of this lane
    int sw0 = ((lg) ^ sA) << 3;             // ks=0: col-chunk lg, swizzled, in shorts
    int sw1 = ((4 + lg) ^ sA) << 3;         // ks=1
    int arow0 = wm * 64 + lane15;
    int brow0 = wn * 128 + lane15;

    // staging source (pre-swizzled global col so linear LDS dest ends up swizzled)
    int rowc = lane >> 3;                   // row within 8-row chunk
    int scol = ((lane & 7) ^ rowc) << 3;    // source col-chunk (shorts)
    const unsigned short* gA = abf + (size_t)(l * M_PAD + mt * 256) * D_DIM;
    const unsigned short* gB = rbf + (size_t)(l * N_PAD + nt * 256) * D_DIM;
    int chA0 = wid, chA1 = 8 + wid, chA2 = 16 + wid, chA3 = 24 + wid;
    int chB0 = (wid < 4) ? (0 + wid) : (12 + wid);
    int chB1 = (wid < 4) ? (4 + wid) : (16 + wid);
    int chB2 = (wid < 4) ? (8 + wid) : (20 + wid);
    int chB3 = (wid < 4) ? (12 + wid) : (24 + wid);
    const unsigned short* pA0 = gA + (size_t)(chA0 * 8 + rowc) * D_DIM + scol;
    const unsigned short* pA1 = gA + (size_t)(chA1 * 8 + rowc) * D_DIM + scol;
    const unsigned short* pA2 = gA + (size_t)(chA2 * 8 + rowc) * D_DIM + scol;
    const unsigned short* pA3 = gA + (size_t)(chA3 * 8 + rowc) * D_DIM + scol;
    const unsigned short* pB0 = gB + (size_t)(chB0 * 8 + rowc) * D_DIM + scol;
    const unsigned short* pB1 = gB + (size_t)(chB1 * 8 + rowc) * D_DIM + scol;
    const unsigned short* pB2 = gB + (size_t)(chB2 * 8 + rowc) * D_DIM + scol;
    const unsigned short* pB3 = gB + (size_t)(chB3 * 8 + rowc) * D_DIM + scol;

    f32x4 acc[4][8];
    #pragma unroll
    for (int mi = 0; mi < 4; ++mi)
        #pragma unroll
        for (int nj = 0; nj < 8; ++nj)
            acc[mi][nj] = f32x4{0.f, 0.f, 0.f, 0.f};

    // prologue: stage K-tile 0 into buf0; need A0..A3 + Bq0 before phase 0
    GLL(pA0, chA0 * 512); GLL(pA1, chA1 * 512);
    GLL(pA2, chA2 * 512); GLL(pA3, chA3 * 512);
    GLL(pB0, 32768 + chB0 * 512); GLL(pB1, 32768 + chB1 * 512);
    GLL(pB2, 32768 + chB2 * 512); GLL(pB3, 32768 + chB3 * 512);
    asm volatile("s_waitcnt vmcnt(3)" ::: "memory");
    __builtin_amdgcn_s_barrier();

    int buf = 0;
    for (int kt = 0; kt < KT; ++kt) {
        int ob = buf ^ 1;
        int aB = buf * 16384;
        int bB = 32768 + buf * 16384;
        int oaB = ob * 16384;
        int obB = 32768 + ob * 16384;
        int koff = (kt + 1 < KT ? kt + 1 : KT - 1) * 64;   // kt=9 restages t9 (dummy)

        // phase 0: read A-all + B quadrant 0; stage A0',A1'
        bf16x8 a[4][2];
        #pragma unroll
        for (int mi = 0; mi < 4; ++mi) {
            a[mi][0] = *(const bf16x8*)(lds + aB + (arow0 + mi * 16) * 64 + sw0);
            a[mi][1] = *(const bf16x8*)(lds + aB + (arow0 + mi * 16) * 64 + sw1);
        }
        PHASE_TAIL(0, GLL(pA0 + koff, oaB + chA0 * 512),
                      GLL(pA1 + koff, oaB + chA1 * 512), "vmcnt(4)")
        // phase 1: B quadrant 1; stage A2',A3'
        PHASE_TAIL(2, GLL(pA2 + koff, oaB + chA2 * 512),
                      GLL(pA3 + koff, oaB + chA3 * 512), "vmcnt(5)")
        // phase 2: B quadrant 2; stage B0',B1'
        PHASE_TAIL(4, GLL(pB0 + koff, obB + chB0 * 512),
                      GLL(pB1 + koff, obB + chB1 * 512), "vmcnt(6)")
        // phase 3: B quadrant 3; stage B2',B3'
        PHASE_TAIL(6, GLL(pB2 + koff, obB + chB2 * 512),
                      GLL(pB3 + koff, obB + chB3 * 512), "vmcnt(3)")
        buf = ob;
    }

    __syncthreads();

    // fused epilogue: mask cols >= 1800, rowmax over the block's 256 cols.
    // C/D layout: col = lane&15, row = (lane>>4)*4 + reg  [m89-verified]
    int colbase = nt * 256 + wn * 128 + lane15;
    #pragma unroll
    for (int mi = 0; mi < 4; ++mi) {
        float t[4] = {-__builtin_inff(), -__builtin_inff(),
                      -__builtin_inff(), -__builtin_inff()};
        #pragma unroll
        for (int nj = 0; nj < 8; ++nj) {
            if (colbase + nj * 16 < R_DIM) {
                #pragma unroll
                for (int r = 0; r < 4; ++r) t[r] = fmaxf(t[r], acc[mi][nj][r]);
            }
        }
        #pragma unroll
        for (int m = 1; m <= 8; m <<= 1) {
            #pragma unroll
            for (int r = 0; r < 4; ++r) t[r] = fmaxf(t[r], __shfl_xor(t[r], m));
        }
        if (lane15 == 0) {
            int rb = wm * 64 + mi * 16 + lg * 4;
            #pragma unroll
            for (int r = 0; r < 4; ++r) red[wn][rb + r] = t[r];
        }
    }
    __syncthreads();
    if (tid < 256) {
        float vmx = fmaxf(red[0][tid], red[1][tid]);
        pmax[((size_t)l * NT + nt) * M_PAD + mt * 256 + tid] = vmx;
    }
}

// ------------------------------------------------------------- K2: combine
__global__ __launch_bounds__(256)
void k_combine(const float* __restrict__ pmax, const float* __restrict__ rnorm,
               float* __restrict__ prm)
{
    int r = blockIdx.x * 256 + threadIdx.x;
    if (r >= M_TOT) return;
    float s = 0.f;
    #pragma unroll
    for (int l = 0; l < L_DIM; ++l) {
        float m = -__builtin_inff();
        #pragma unroll
        for (int t = 0; t < NT; ++t)
            m = fmaxf(m, pmax[((size_t)l * NT + t) * M_PAD + r]);
        s += m * rnorm[l * M_TOT + r];
    }
    prm[r] = (3.0f - s) / 6.0f;   // mean_l (1 - sim)/2
}

// ------------------------------------------------------------- K3: small net
__device__ __forceinline__ float block_sum(float v, volatile float* scratch) {
    #pragma unroll
    for (int m = 32; m; m >>= 1) v += __shfl_xor(v, m);
    int w = threadIdx.x >> 6;
    __syncthreads();
    if ((threadIdx.x & 63) == 0) scratch[w] = v;
    __syncthreads();
    return scratch[0] + scratch[1] + scratch[2] + scratch[3];
}
__device__ __forceinline__ float block_max(float v, volatile float* scratch) {
    #pragma unroll
    for (int m = 32; m; m >>= 1) v = fmaxf(v, __shfl_xor(v, m));
    int w = threadIdx.x >> 6;
    __syncthreads();
    if ((threadIdx.x & 63) == 0) scratch[w] = v;
    __syncthreads();
    return fmaxf(fmaxf(scratch[0], scratch[1]), fmaxf(scratch[2], scratch[3]));
}

__global__ __launch_bounds__(256)
void k_small(const float* __restrict__ ie, const float* __restrict__ te,
             const float* __restrict__ ier,
             const float* __restrict__ a_w1, const float* __restrict__ a_w2,
             const float* __restrict__ r_w1, const float* __restrict__ r_b1,
             const float* __restrict__ r_g2, const float* __restrict__ r_be2,
             const float* __restrict__ r_w2, const float* __restrict__ r_b2,
             const float* __restrict__ r_g3, const float* __restrict__ r_be3,
             const float* __restrict__ r_w3, const float* __restrict__ r_b3,
             const float* __restrict__ h_w1, const float* __restrict__ h_b1,
             const float* __restrict__ h_g2, const float* __restrict__ h_be2,
             const float* __restrict__ h_w2, const float* __restrict__ h_b2,
             const float* __restrict__ h_g3, const float* __restrict__ h_be3,
             const float* __restrict__ h_w3, const float* __restrict__ h_b3,
             const float* __restrict__ prm, float* __restrict__ heat,
             float* __restrict__ out_score)
{
    int b = blockIdx.x, tid = threadIdx.x;
    __shared__ float x[D_DIM];
    __shared__ float h1[160];
    __shared__ float dif[D_DIM];
    __shared__ float z1[128];
    __shared__ float z2[64];
    __shared__ float hol[P_DIM];
    __shared__ float rcp[P_DIM];
    __shared__ float scratch[4];

    for (int i = tid; i < D_DIM; i += 256) x[i] = ie[b * D_DIM + i];
    __syncthreads();

    float ss = 0.f, d0 = 0.f, d1 = 0.f;
    for (int i = tid; i < D_DIM; i += 256) {
        float v = x[i];
        ss += v * v;
        d0 += v * te[i];
        d1 += v * te[D_DIM + i];
    }
    float ssum = block_sum(ss, scratch);
    float dd0 = block_sum(d0, scratch);
    float dd1 = block_sum(d1, scratch);
    float tscore = 1.f / (1.f + expf(100.f * rsqrtf(ssum) * (dd0 - dd1)));

    for (int o = tid; o < 160; o += 256) {
        const float* w = a_w1 + (size_t)o * D_DIM;
        float s0 = 0, s1 = 0, s2 = 0, s3 = 0;
        for (int d = 0; d < D_DIM; d += 4) {
            s0 += x[d] * w[d]; s1 += x[d + 1] * w[d + 1];
            s2 += x[d + 2] * w[d + 2]; s3 += x[d + 3] * w[d + 3];
        }
        h1[o] = fmaxf((s0 + s1) + (s2 + s3), 0.f);
    }
    __syncthreads();
    for (int d = tid; d < D_DIM; d += 256) {
        const float* w = a_w2 + (size_t)d * 160;
        float s0 = 0, s1 = 0, s2 = 0, s3 = 0;
        for (int o = 0; o < 160; o += 4) {
            s0 += h1[o] * w[o]; s1 += h1[o + 1] * w[o + 1];
            s2 += h1[o + 2] * w[o + 2]; s3 += h1[o + 3] * w[o + 3];
        }
        dif[d] = ier[d] - fmaxf((s0 + s1) + (s2 + s3), 0.f);
    }
    __syncthreads();

    for (int o = tid; o < 128; o += 256) {
        const float* w = r_w1 + (size_t)o * D_DIM;
        float s0 = 0, s1 = 0, s2 = 0, s3 = 0;
        for (int d = 0; d < D_DIM; d += 4) {
            s0 += dif[d] * w[d]; s1 += dif[d + 1] * w[d + 1];
            s2 += dif[d + 2] * w[d + 2]; s3 += dif[d + 3] * w[d + 3];
        }
        float s = (s0 + s1) + (s2 + s3) + r_b1[o];
        z1[o] = fmaxf(s, 0.f) * (r_g2[o] * BNSCALE) + r_be2[o];
    }
    __syncthreads();
    for (int o = tid; o < 64; o += 256) {
        const float* w = r_w2 + (size_t)o * 128;
        float s = r_b2[o];
        for (int d = 0; d < 128; ++d) s += z1[d] * w[d];
        z2[o] = fmaxf(s, 0.f) * (r_g3[o] * BNSCALE) + r_be3[o];
    }
    __syncthreads();
    float sp = (tid < 64) ? z2[tid] * r_w3[tid] : 0.f;
    float irs = 1.f / (1.f + expf(-(block_sum(sp, scratch) + r_b3[0])));

    float fgp = -__builtin_inff();
    float base = tscore + irs;
    for (int p = tid; p < P_DIM; p += 256) {
        float pv = prm[b * P_DIM + p];
        fgp = fmaxf(fgp, pv);
        float h = base + pv;
        hol[p] = h;
        rcp[p] = 1.f / h;
    }
    float fg = block_max(fgp, scratch);

    for (int o = tid; o < 128; o += 256) {
        const float* w = h_w1 + (size_t)o * P_DIM;
        float s = h_b1[o];
        for (int d = 0; d < P_DIM; ++d) s += hol[d] * w[d];
        z1[o] = fmaxf(s, 0.f) * (h_g2[o] * BNSCALE) + h_be2[o];
    }
    __syncthreads();
    for (int o = tid; o < 64; o += 256) {
        const float* w = h_w2 + (size_t)o * 128;
        float s = h_b2[o];
        for (int d = 0; d < 128; ++d) s += z1[d] * w[d];
        z2[o] = fmaxf(s, 0.f) * (h_g3[o] * BNSCALE) + h_be3[o];
    }
    __syncthreads();
    float sp2 = (tid < 64) ? z2[tid] * h_w3[tid] : 0.f;
    float hl_in = block_sum(sp2, scratch) + h_b3[0];
    if (tid == 0) {
        float hl = 1.f / (1.f + expf(-hl_in));
        out_score[b] = (hl + fg) * 0.5f;
    }

    {
        int r = tid >> 4, c = tid & 15;
        float s = 0.f, cnt = 0.f;
        #pragma unroll
        for (int di = -1; di <= 0; ++di) {
            int i = r + di;
            if (i < 0 || i > 14) continue;
            #pragma unroll
            for (int dj = -1; dj <= 0; ++dj) {
                int j = c + dj;
                if (j < 0 || j > 14) continue;
                s += rcp[i * 15 + j];
                cnt += 1.f;
            }
        }
        heat[b * 256 + tid] = cnt / s;
    }
}

// ------------------------------------------------------------- K4: resize
// jax bilinear 16->240 == clamped half-pixel sampling: s=(o-7)/15.
__global__ __launch_bounds__(256)
void k_resize(const float* __restrict__ heat, float* __restrict__ outh)
{
    int b = blockIdx.x >> 3, sub = blockIdx.x & 7;
    __shared__ float h[256];
    if (threadIdx.x < 256) h[threadIdx.x] = heat[b * 256 + threadIdx.x];
    __syncthreads();
    int base = sub * 30 * S_DIM;
    for (int q = threadIdx.x; q < 30 * S_DIM; q += 256) {
        int px = base + q;
        int y = px / S_DIM, xc = px - y * S_DIM;
        float sy = fminf(fmaxf((y - 7) * (1.0f / 15.0f), 0.f), 15.f);
        float sx = fminf(fmaxf((xc - 7) * (1.0f / 15.0f), 0.f), 15.f);
        int y0 = (int)sy, x0 = (int)sx;
        int y1 = min(y0 + 1, 15), x1 = min(x0 + 1, 15);
        float fy = sy - (float)y0, fx = sx - (float)x0;
        float v00 = h[y0 * 16 + x0], v01 = h[y0 * 16 + x1];
        float v10 = h[y1 * 16 + x0], v11 = h[y1 * 16 + x1];
        float v = (1.f - fy) * ((1.f - fx) * v00 + fx * v01)
                + fy * ((1.f - fx) * v10 + fx * v11);
        outh[(size_t)b * (S_DIM * S_DIM) + px] = v;
    }
}

// ---------------------------------------------------------------- launcher
extern "C" void kernel_launch(void* const* d_in, const int* in_sizes, int n_in,
                              void* d_out, int out_size, void* d_ws, size_t ws_size,
                              hipStream_t stream)
{
    (void)in_sizes; (void)n_in; (void)out_size; (void)ws_size;
    const float* image_embeds = (const float*)d_in[1];
    const float* patch_embeds = (const float*)d_in[2];
    const float* text_embeds  = (const float*)d_in[3];
    const float* ier          = (const float*)d_in[4];
    const float* per          = (const float*)d_in[5];
    const float* a_w1 = (const float*)d_in[6];
    const float* a_w2 = (const float*)d_in[7];
    const float* r_w1 = (const float*)d_in[8];
    const float* r_b1 = (const float*)d_in[9];
    const float* r_g2 = (const float*)d_in[10];
    const float* r_be2 = (const float*)d_in[11];
    const float* r_w2 = (const float*)d_in[12];
    const float* r_b2 = (const float*)d_in[13];
    const float* r_g3 = (const float*)d_in[14];
    const float* r_be3 = (const float*)d_in[15];
    const float* r_w3 = (const float*)d_in[16];
    const float* r_b3 = (const float*)d_in[17];
    const float* h_w1 = (const float*)d_in[18];
    const float* h_b1 = (const float*)d_in[19];
    const float* h_g2 = (const float*)d_in[20];
    const float* h_be2 = (const float*)d_in[21];
    const float* h_w2 = (const float*)d_in[22];
    const float* h_b2 = (const float*)d_in[23];
    const float* h_g3 = (const float*)d_in[24];
    const float* h_be3 = (const float*)d_in[25];
    const float* h_w3 = (const float*)d_in[26];
    const float* h_b3 = (const float*)d_in[27];

    char* ws = (char*)d_ws;
    size_t off = 0;
    auto take = [&](size_t bytes) -> void* {
        void* p = ws + off;
        off += (bytes + 255) & ~(size_t)255;
        return p;
    };
    float* rnorm = (float*)take((size_t)L_DIM * M_TOT * 4);            // 173 KB
    float* pmax  = (float*)take((size_t)L_DIM * NT * M_PAD * 4);       // 1.4 MB
    float* prm   = (float*)take((size_t)M_TOT * 4);                    // 58 KB
    float* heat  = (float*)take((size_t)B_DIM * 256 * 4);              // 64 KB
    unsigned short* abf = (unsigned short*)take((size_t)L_DIM * M_PAD * D_DIM * 2); // 56.0 MB
    unsigned short* rbf = (unsigned short*)take((size_t)L_DIM * N_PAD * D_DIM * 2); //  7.9 MB

    float* out_f = (float*)d_out;  // [64] final_score || [64*240*240] hmap, f32

    k_convert<<<dim3((L_DIM * M_PAD + L_DIM * N_PAD) / 4), dim3(256), 0, stream>>>(
        patch_embeds, per, abf, rbf, rnorm);
    k_gemm_max<<<dim3(L_DIM * MT * NT), dim3(512), 0, stream>>>(abf, rbf, pmax);
    k_combine<<<dim3((M_TOT + 255) / 256), dim3(256), 0, stream>>>(pmax, rnorm, prm);
    k_small<<<dim3(B_DIM), dim3(256), 0, stream>>>(image_embeds, text_embeds, ier,
        a_w1, a_w2, r_w1, r_b1, r_g2, r_be2, r_w2, r_b2, r_g3, r_be3, r_w3, r_b3,
        h_w1, h_b1, h_g2, h_be2, h_w2, h_b2, h_g3, h_be3, h_w3, h_b3,
        prm, heat, out_f);
    k_resize<<<dim3(B_DIM * 8), dim3(256), 0, stream>>>(heat, out_f + B_DIM);
}

// Round 6
// 204.484 us; speedup vs baseline: 3.3887x; 1.0160x over previous
//
#include <hip/hip_runtime.h>
#include <stdint.h>
#include <math.h>

#define L_DIM 3
#define B_DIM 64
#define P_DIM 225
#define D_DIM 640
#define R_DIM 1800
#define S_DIM 240
#define M_TOT 14400
#define M_PAD 14592             /* 57*256 */
#define N_PAD 2048              /* 8*256 */
#define MT 57
#define NT 8
#define KT 10                   /* 640/64 */
#define BNSCALE 0.99999500003749981f  /* 1/sqrt(1+1e-5) */

typedef __bf16 bf16x8 __attribute__((ext_vector_type(8)));
typedef float f32x4 __attribute__((ext_vector_type(4)));

__device__ __forceinline__ unsigned short f2bf(float f) {
    union { float f; unsigned u; } v; v.f = f;
    unsigned u = v.u;
    unsigned r = (u + 0x7FFFu + ((u >> 16) & 1u)) >> 16;   // RNE
    return (unsigned short)r;
}

// ---------------------------------------------------------------- K0: convert
// one wave per 640-elem row, float4 loads / ushort4 stores; A rows fuse rsqrt(sum x^2).
__global__ __launch_bounds__(256)
void k_convert(const float* __restrict__ pe, const float* __restrict__ per,
               unsigned short* __restrict__ abf, unsigned short* __restrict__ rbf,
               float* __restrict__ rnorm)
{
    const int AROWS = L_DIM * M_PAD;            // 43776
    int wid = (blockIdx.x * 256 + threadIdx.x) >> 6;
    int lane = threadIdx.x & 63;
    const ushort4 z4 = {0, 0, 0, 0};
    if (wid < AROWS) {
        int l = wid / M_PAD, r = wid - l * M_PAD;
        unsigned short* dst = abf + (size_t)wid * D_DIM;
        if (r < M_TOT) {
            const float4* src = (const float4*)(pe + ((size_t)l * M_TOT + r) * D_DIM);
            float ss = 0.f;
            #pragma unroll
            for (int it = 0; it < 3; ++it) {
                int idx = it * 64 + lane;
                if (idx < 160) {
                    float4 v = src[idx];
                    ss += v.x * v.x + v.y * v.y + v.z * v.z + v.w * v.w;
                    ushort4 o;
                    o.x = f2bf(v.x); o.y = f2bf(v.y); o.z = f2bf(v.z); o.w = f2bf(v.w);
                    *(ushort4*)(dst + idx * 4) = o;
                }
            }
            #pragma unroll
            for (int m = 32; m; m >>= 1) ss += __shfl_xor(ss, m);
            if (lane == 0) rnorm[l * M_TOT + r] = rsqrtf(ss);
        } else {                                 // zero pad rows
            #pragma unroll
            for (int it = 0; it < 3; ++it) {
                int idx = it * 64 + lane;
                if (idx < 160) *(ushort4*)(dst + idx * 4) = z4;
            }
        }
    } else {
        int w2 = wid - AROWS;
        int l = w2 / N_PAD, r = w2 - l * N_PAD;
        unsigned short* dst = rbf + (size_t)w2 * D_DIM;
        if (r < R_DIM) {
            const float4* src = (const float4*)(per + ((size_t)l * R_DIM + r) * D_DIM);
            #pragma unroll
            for (int it = 0; it < 3; ++it) {
                int idx = it * 64 + lane;
                if (idx < 160) {
                    float4 v = src[idx];
                    ushort4 o;
                    o.x = f2bf(v.x); o.y = f2bf(v.y); o.z = f2bf(v.z); o.w = f2bf(v.w);
                    *(ushort4*)(dst + idx * 4) = o;
                }
            }
        } else {
            #pragma unroll
            for (int it = 0; it < 3; ++it) {
                int idx = it * 64 + lane;
                if (idx < 160) *(ushort4*)(dst + idx * 4) = z4;
            }
        }
    }
}

// ----------------------------------- K1: 256^2 4-phase bf16 GEMM + fused rowmax
// T1 XCD swizzle + T2 LDS XOR swizzle + T3/T4 counted-vmcnt pipeline + T5.
// SINGLE barrier per phase: each phase's ds_reads are covered by the PREVIOUS
// phase's vmcnt+barrier; GLLs always write the opposite buffer; MFMA is reg-only.
#define MFMA(A, B, C) __builtin_amdgcn_mfma_f32_16x16x32_bf16((A), (B), (C), 0, 0, 0)
#define GLL(SRC, DSTOFF)                                                     \
    __builtin_amdgcn_global_load_lds(                                        \
        (const __attribute__((address_space(1))) void*)(SRC),               \
        (__attribute__((address_space(3))) void*)(lds + (DSTOFF)), 16, 0, 0)

#define PHASE_TAIL(NJB, STG0, STG1, VMSTR)                                   \
    {                                                                        \
        bf16x8 b00 = *(const bf16x8*)(lds + bB + (brow0 + (NJB) * 16) * 64 + sw0);     \
        bf16x8 b01 = *(const bf16x8*)(lds + bB + (brow0 + (NJB) * 16) * 64 + sw1);     \
        bf16x8 b10 = *(const bf16x8*)(lds + bB + (brow0 + (NJB + 1) * 16) * 64 + sw0); \
        bf16x8 b11 = *(const bf16x8*)(lds + bB + (brow0 + (NJB + 1) * 16) * 64 + sw1); \
        STG0; STG1;                                                          \
        asm volatile("s_waitcnt " VMSTR ::: "memory");                       \
        __builtin_amdgcn_s_barrier();                                        \
        __builtin_amdgcn_s_setprio(1);                                       \
        _Pragma("unroll")                                                    \
        for (int mi = 0; mi < 4; ++mi) {                                     \
            acc[mi][NJB]     = MFMA(a[mi][0], b00, acc[mi][NJB]);            \
            acc[mi][NJB]     = MFMA(a[mi][1], b01, acc[mi][NJB]);            \
            acc[mi][NJB + 1] = MFMA(a[mi][0], b10, acc[mi][NJB + 1]);        \
            acc[mi][NJB + 1] = MFMA(a[mi][1], b11, acc[mi][NJB + 1]);        \
        }                                                                    \
        __builtin_amdgcn_s_setprio(0);                                       \
    }

__global__ __launch_bounds__(512, 2)
void k_gemm_max(const unsigned short* __restrict__ abf,
                const unsigned short* __restrict__ rbf,
                float* __restrict__ pmax)
{
    __shared__ unsigned short lds[65536];   // A: [0,32768) 2 bufs; B: [32768,65536)
    __shared__ float red[2][256];

    // XCD-chunked bijective swizzle: 1368 blocks = 8 XCDs * 171
    int bid = blockIdx.x;
    int v = (bid & 7) * 171 + (bid >> 3);
    int l = v / (MT * NT);
    int rem = v - l * (MT * NT);
    int mt = rem >> 3;
    int nt = rem & 7;

    int tid = threadIdx.x;
    int wid = tid >> 6, lane = tid & 63;
    int wm = wid >> 1;                      // 0..3 -> rows wm*64..+64
    int wn = wid & 1;                       // 0..1 -> cols wn*128..+128
    int lane15 = lane & 15, lg = lane >> 4;
    int sA = lane15 & 7;                    // row&7 for all frag rows of this lane
    int sw0 = ((lg) ^ sA) << 3;             // ks=0: swizzled col-chunk, in shorts
    int sw1 = ((4 + lg) ^ sA) << 3;         // ks=1
    int arow0 = wm * 64 + lane15;
    int brow0 = wn * 128 + lane15;

    // staging source (pre-swizzled global col so linear LDS dest ends up swizzled)
    int rowc = lane >> 3;                   // row within 8-row chunk
    int scol = ((lane & 7) ^ rowc) << 3;    // source col-chunk (shorts)
    const unsigned short* gA = abf + (size_t)(l * M_PAD + mt * 256) * D_DIM;
    const unsigned short* gB = rbf + (size_t)(l * N_PAD + nt * 256) * D_DIM;
    int chA0 = wid, chA1 = 8 + wid, chA2 = 16 + wid, chA3 = 24 + wid;
    int chB0 = (wid < 4) ? (0 + wid) : (12 + wid);
    int chB1 = (wid < 4) ? (4 + wid) : (16 + wid);
    int chB2 = (wid < 4) ? (8 + wid) : (20 + wid);
    int chB3 = (wid < 4) ? (12 + wid) : (24 + wid);
    const unsigned short* pA0 = gA + (size_t)(chA0 * 8 + rowc) * D_DIM + scol;
    const unsigned short* pA1 = gA + (size_t)(chA1 * 8 + rowc) * D_DIM + scol;
    const unsigned short* pA2 = gA + (size_t)(chA2 * 8 + rowc) * D_DIM + scol;
    const unsigned short* pA3 = gA + (size_t)(chA3 * 8 + rowc) * D_DIM + scol;
    const unsigned short* pB0 = gB + (size_t)(chB0 * 8 + rowc) * D_DIM + scol;
    const unsigned short* pB1 = gB + (size_t)(chB1 * 8 + rowc) * D_DIM + scol;
    const unsigned short* pB2 = gB + (size_t)(chB2 * 8 + rowc) * D_DIM + scol;
    const unsigned short* pB3 = gB + (size_t)(chB3 * 8 + rowc) * D_DIM + scol;

    f32x4 acc[4][8];
    #pragma unroll
    for (int mi = 0; mi < 4; ++mi)
        #pragma unroll
        for (int nj = 0; nj < 8; ++nj)
            acc[mi][nj] = f32x4{0.f, 0.f, 0.f, 0.f};

    // prologue: stage K-tile 0 into buf0; need A0..A3 + Bq0 before phase 0
    GLL(pA0, chA0 * 512); GLL(pA1, chA1 * 512);
    GLL(pA2, chA2 * 512); GLL(pA3, chA3 * 512);
    GLL(pB0, 32768 + chB0 * 512); GLL(pB1, 32768 + chB1 * 512);
    GLL(pB2, 32768 + chB2 * 512); GLL(pB3, 32768 + chB3 * 512);
    asm volatile("s_waitcnt vmcnt(3)" ::: "memory");
    __builtin_amdgcn_s_barrier();

    int buf = 0;
    for (int kt = 0; kt < KT; ++kt) {
        int ob = buf ^ 1;
        int aB = buf * 16384;
        int bB = 32768 + buf * 16384;
        int oaB = ob * 16384;
        int obB = 32768 + ob * 16384;
        int koff = (kt + 1 < KT ? kt + 1 : KT - 1) * 64;   // kt=9 restages t9 (dummy)

        // phase 0: read A-all + B quadrant 0; stage A0',A1'
        bf16x8 a[4][2];
        #pragma unroll
        for (int mi = 0; mi < 4; ++mi) {
            a[mi][0] = *(const bf16x8*)(lds + aB + (arow0 + mi * 16) * 64 + sw0);
            a[mi][1] = *(const bf16x8*)(lds + aB + (arow0 + mi * 16) * 64 + sw1);
        }
        PHASE_TAIL(0, GLL(pA0 + koff, oaB + chA0 * 512),
                      GLL(pA1 + koff, oaB + chA1 * 512), "vmcnt(4)")
        // phase 1: B quadrant 1; stage A2',A3'
        PHASE_TAIL(2, GLL(pA2 + koff, oaB + chA2 * 512),
                      GLL(pA3 + koff, oaB + chA3 * 512), "vmcnt(5)")
        // phase 2: B quadrant 2; stage B0',B1'
        PHASE_TAIL(4, GLL(pB0 + koff, obB + chB0 * 512),
                      GLL(pB1 + koff, obB + chB1 * 512), "vmcnt(6)")
        // phase 3: B quadrant 3; stage B2',B3'
        PHASE_TAIL(6, GLL(pB2 + koff, obB + chB2 * 512),
                      GLL(pB3 + koff, obB + chB3 * 512), "vmcnt(3)")
        buf = ob;
    }

    __syncthreads();

    // fused epilogue: mask cols >= 1800, rowmax over the block's 256 cols.
    // C/D layout: col = lane&15, row = (lane>>4)*4 + reg  [m89-verified]
    int colbase = nt * 256 + wn * 128 + lane15;
    #pragma unroll
    for (int mi = 0; mi < 4; ++mi) {
        float t[4] = {-__builtin_inff(), -__builtin_inff(),
                      -__builtin_inff(), -__builtin_inff()};
        #pragma unroll
        for (int nj = 0; nj < 8; ++nj) {
            if (colbase + nj * 16 < R_DIM) {
                #pragma unroll
                for (int r = 0; r < 4; ++r) t[r] = fmaxf(t[r], acc[mi][nj][r]);
            }
        }
        #pragma unroll
        for (int m = 1; m <= 8; m <<= 1) {
            #pragma unroll
            for (int r = 0; r < 4; ++r) t[r] = fmaxf(t[r], __shfl_xor(t[r], m));
        }
        if (lane15 == 0) {
            int rb = wm * 64 + mi * 16 + lg * 4;
            #pragma unroll
            for (int r = 0; r < 4; ++r) red[wn][rb + r] = t[r];
        }
    }
    __syncthreads();
    if (tid < 256) {
        float vmx = fmaxf(red[0][tid], red[1][tid]);
        pmax[((size_t)l * NT + nt) * M_PAD + mt * 256 + tid] = vmx;
    }
}

// ------------------------------------------------------------- K2: combine
__global__ __launch_bounds__(256)
void k_combine(const float* __restrict__ pmax, const float* __restrict__ rnorm,
               float* __restrict__ prm)
{
    int r = blockIdx.x * 256 + threadIdx.x;
    if (r >= M_TOT) return;
    float s = 0.f;
    #pragma unroll
    for (int l = 0; l < L_DIM; ++l) {
        float m = -__builtin_inff();
        #pragma unroll
        for (int t = 0; t < NT; ++t)
            m = fmaxf(m, pmax[((size_t)l * NT + t) * M_PAD + r]);
        s += m * rnorm[l * M_TOT + r];
    }
    prm[r] = (3.0f - s) / 6.0f;   // mean_l (1 - sim)/2
}

// ------------------------------------------------------------- K3: small net (512 thr)
__device__ __forceinline__ float block_sum8(float v, volatile float* scratch) {
    #pragma unroll
    for (int m = 32; m; m >>= 1) v += __shfl_xor(v, m);
    int w = threadIdx.x >> 6;
    __syncthreads();
    if ((threadIdx.x & 63) == 0) scratch[w] = v;
    __syncthreads();
    float r = 0.f;
    #pragma unroll
    for (int i = 0; i < 8; ++i) r += scratch[i];
    return r;
}
__device__ __forceinline__ float block_max8(float v, volatile float* scratch) {
    #pragma unroll
    for (int m = 32; m; m >>= 1) v = fmaxf(v, __shfl_xor(v, m));
    int w = threadIdx.x >> 6;
    __syncthreads();
    if ((threadIdx.x & 63) == 0) scratch[w] = v;
    __syncthreads();
    float r = scratch[0];
    #pragma unroll
    for (int i = 1; i < 8; ++i) r = fmaxf(r, scratch[i]);
    return r;
}

__global__ __launch_bounds__(512)
void k_small(const float* __restrict__ ie, const float* __restrict__ te,
             const float* __restrict__ ier,
             const float* __restrict__ a_w1, const float* __restrict__ a_w2,
             const float* __restrict__ r_w1, const float* __restrict__ r_b1,
             const float* __restrict__ r_g2, const float* __restrict__ r_be2,
             const float* __restrict__ r_w2, const float* __restrict__ r_b2,
             const float* __restrict__ r_g3, const float* __restrict__ r_be3,
             const float* __restrict__ r_w3, const float* __restrict__ r_b3,
             const float* __restrict__ h_w1, const float* __restrict__ h_b1,
             const float* __restrict__ h_g2, const float* __restrict__ h_be2,
             const float* __restrict__ h_w2, const float* __restrict__ h_b2,
             const float* __restrict__ h_g3, const float* __restrict__ h_be3,
             const float* __restrict__ h_w3, const float* __restrict__ h_b3,
             const float* __restrict__ prm, float* __restrict__ heat,
             float* __restrict__ out_score)
{
    int b = blockIdx.x, tid = threadIdx.x;
    __shared__ float x[D_DIM];
    __shared__ float h1[160];
    __shared__ float dif[D_DIM];
    __shared__ float z1[128];
    __shared__ float z2[64];
    __shared__ float hol[P_DIM];
    __shared__ float rcp[P_DIM];
    __shared__ float scratch[8];

    for (int i = tid; i < D_DIM; i += 512) x[i] = ie[b * D_DIM + i];
    __syncthreads();

    float ss = 0.f, d0 = 0.f, d1 = 0.f;
    for (int i = tid; i < D_DIM; i += 512) {
        float v = x[i];
        ss += v * v;
        d0 += v * te[i];
        d1 += v * te[D_DIM + i];
    }
    float ssum = block_sum8(ss, scratch);
    float dd0 = block_sum8(d0, scratch);
    float dd1 = block_sum8(d1, scratch);
    float tscore = 1.f / (1.f + expf(100.f * rsqrtf(ssum) * (dd0 - dd1)));

    for (int o = tid; o < 160; o += 512) {
        const float* w = a_w1 + (size_t)o * D_DIM;
        float s0 = 0, s1 = 0, s2 = 0, s3 = 0;
        for (int d = 0; d < D_DIM; d += 4) {
            s0 += x[d] * w[d]; s1 += x[d + 1] * w[d + 1];
            s2 += x[d + 2] * w[d + 2]; s3 += x[d + 3] * w[d + 3];
        }
        h1[o] = fmaxf((s0 + s1) + (s2 + s3), 0.f);
    }
    __syncthreads();
    for (int d = tid; d < D_DIM; d += 512) {
        const float* w = a_w2 + (size_t)d * 160;
        float s0 = 0, s1 = 0, s2 = 0, s3 = 0;
        for (int o = 0; o < 160; o += 4) {
            s0 += h1[o] * w[o]; s1 += h1[o + 1] * w[o + 1];
            s2 += h1[o + 2] * w[o + 2]; s3 += h1[o + 3] * w[o + 3];
        }
        dif[d] = ier[d] - fmaxf((s0 + s1) + (s2 + s3), 0.f);
    }
    __syncthreads();

    for (int o = tid; o < 128; o += 512) {
        const float* w = r_w1 + (size_t)o * D_DIM;
        float s0 = 0, s1 = 0, s2 = 0, s3 = 0;
        for (int d = 0; d < D_DIM; d += 4) {
            s0 += dif[d] * w[d]; s1 += dif[d + 1] * w[d + 1];
            s2 += dif[d + 2] * w[d + 2]; s3 += dif[d + 3] * w[d + 3];
        }
        float s = (s0 + s1) + (s2 + s3) + r_b1[o];
        z1[o] = fmaxf(s, 0.f) * (r_g2[o] * BNSCALE) + r_be2[o];
    }
    __syncthreads();
    for (int o = tid; o < 64; o += 512) {
        const float* w = r_w2 + (size_t)o * 128;
        float s = r_b2[o];
        for (int d = 0; d < 128; ++d) s += z1[d] * w[d];
        z2[o] = fmaxf(s, 0.f) * (r_g3[o] * BNSCALE) + r_be3[o];
    }
    __syncthreads();
    float sp = (tid < 64) ? z2[tid] * r_w3[tid] : 0.f;
    float irs = 1.f / (1.f + expf(-(block_sum8(sp, scratch) + r_b3[0])));

    float fgp = -__builtin_inff();
    float base = tscore + irs;
    for (int p = tid; p < P_DIM; p += 512) {
        float pv = prm[b * P_DIM + p];
        fgp = fmaxf(fgp, pv);
        float h = base + pv;
        hol[p] = h;
        rcp[p] = 1.f / h;
    }
    float fg = block_max8(fgp, scratch);

    for (int o = tid; o < 128; o += 512) {
        const float* w = h_w1 + (size_t)o * P_DIM;
        float s = h_b1[o];
        for (int d = 0; d < P_DIM; ++d) s += hol[d] * w[d];
        z1[o] = fmaxf(s, 0.f) * (h_g2[o] * BNSCALE) + h_be2[o];
    }
    __syncthreads();
    for (int o = tid; o < 64; o += 512) {
        const float* w = h_w2 + (size_t)o * 128;
        float s = h_b2[o];
        for (int d = 0; d < 128; ++d) s += z1[d] * w[d];
        z2[o] = fmaxf(s, 0.f) * (h_g3[o] * BNSCALE) + h_be3[o];
    }
    __syncthreads();
    float sp2 = (tid < 64) ? z2[tid] * h_w3[tid] : 0.f;
    float hl_in = block_sum8(sp2, scratch) + h_b3[0];
    if (tid == 0) {
        float hl = 1.f / (1.f + expf(-hl_in));
        out_score[b] = (hl + fg) * 0.5f;
    }

    if (tid < 256) {
        int r = tid >> 4, c = tid & 15;
        float s = 0.f, cnt = 0.f;
        #pragma unroll
        for (int di = -1; di <= 0; ++di) {
            int i = r + di;
            if (i < 0 || i > 14) continue;
            #pragma unroll
            for (int dj = -1; dj <= 0; ++dj) {
                int j = c + dj;
                if (j < 0 || j > 14) continue;
                s += rcp[i * 15 + j];
                cnt += 1.f;
            }
        }
        heat[b * 256 + tid] = cnt / s;
    }
}

// ------------------------------------------------------------- K4: resize
// jax bilinear 16->240 == clamped half-pixel sampling: s=(o-7)/15.
__global__ __launch_bounds__(256)
void k_resize(const float* __restrict__ heat, float* __restrict__ outh)
{
    int b = blockIdx.x >> 3, sub = blockIdx.x & 7;
    __shared__ float h[256];
    if (threadIdx.x < 256) h[threadIdx.x] = heat[b * 256 + threadIdx.x];
    __syncthreads();
    int base = sub * 30 * S_DIM;
    for (int q = threadIdx.x; q < 30 * S_DIM; q += 256) {
        int px = base + q;
        int y = px / S_DIM, xc = px - y * S_DIM;
        float sy = fminf(fmaxf((y - 7) * (1.0f / 15.0f), 0.f), 15.f);
        float sx = fminf(fmaxf((xc - 7) * (1.0f / 15.0f), 0.f), 15.f);
        int y0 = (int)sy, x0 = (int)sx;
        int y1 = min(y0 + 1, 15), x1 = min(x0 + 1, 15);
        float fy = sy - (float)y0, fx = sx - (float)x0;
        float v00 = h[y0 * 16 + x0], v01 = h[y0 * 16 + x1];
        float v10 = h[y1 * 16 + x0], v11 = h[y1 * 16 + x1];
        float v = (1.f - fy) * ((1.f - fx) * v00 + fx * v01)
                + fy * ((1.f - fx) * v10 + fx * v11);
        outh[(size_t)b * (S_DIM * S_DIM) + px] = v;
    }
}

// ---------------------------------------------------------------- launcher
extern "C" void kernel_launch(void* const* d_in, const int* in_sizes, int n_in,
                              void* d_out, int out_size, void* d_ws, size_t ws_size,
                              hipStream_t stream)
{
    (void)in_sizes; (void)n_in; (void)out_size; (void)ws_size;
    const float* image_embeds = (const float*)d_in[1];
    const float* patch_embeds = (const float*)d_in[2];
    const float* text_embeds  = (const float*)d_in[3];
    const float* ier          = (const float*)d_in[4];
    const float* per          = (const float*)d_in[5];
    const float* a_w1 = (const float*)d_in[6];
    const float* a_w2 = (const float*)d_in[7];
    const float* r_w1 = (const float*)d_in[8];
    const float* r_b1 = (const float*)d_in[9];
    const float* r_g2 = (const float*)d_in[10];
    const float* r_be2 = (const float*)d_in[11];
    const float* r_w2 = (const float*)d_in[12];
    const float* r_b2 = (const float*)d_in[13];
    const float* r_g3 = (const float*)d_in[14];
    const float* r_be3 = (const float*)d_in[15];
    const float* r_w3 = (const float*)d_in[16];
    const float* r_b3 = (const float*)d_in[17];
    const float* h_w1 = (const float*)d_in[18];
    const float* h_b1 = (const float*)d_in[19];
    const float* h_g2 = (const float*)d_in[20];
    const float* h_be2 = (const float*)d_in[21];
    const float* h_w2 = (const float*)d_in[22];
    const float* h_b2 = (const float*)d_in[23];
    const float* h_g3 = (const float*)d_in[24];
    const float* h_be3 = (const float*)d_in[25];
    const float* h_w3 = (const float*)d_in[26];
    const float* h_b3 = (const float*)d_in[27];

    char* ws = (char*)d_ws;
    size_t off = 0;
    auto take = [&](size_t bytes) -> void* {
        void* p = ws + off;
        off += (bytes + 255) & ~(size_t)255;
        return p;
    };
    float* rnorm = (float*)take((size_t)L_DIM * M_TOT * 4);            // 173 KB
    float* pmax  = (float*)take((size_t)L_DIM * NT * M_PAD * 4);       // 1.4 MB
    float* prm   = (float*)take((size_t)M_TOT * 4);                    // 58 KB
    float* heat  = (float*)take((size_t)B_DIM * 256 * 4);              // 64 KB
    unsigned short* abf = (unsigned short*)take((size_t)L_DIM * M_PAD * D_DIM * 2); // 56.0 MB
    unsigned short* rbf = (unsigned short*)take((size_t)L_DIM * N_PAD * D_DIM * 2); //  7.9 MB

    float* out_f = (float*)d_out;  // [64] final_score || [64*240*240] hmap, f32

    k_convert<<<dim3((L_DIM * M_PAD + L_DIM * N_PAD) / 4), dim3(256), 0, stream>>>(
        patch_embeds, per, abf, rbf, rnorm);
    k_gemm_max<<<dim3(L_DIM * MT * NT), dim3(512), 0, stream>>>(abf, rbf, pmax);
    k_combine<<<dim3((M_TOT + 255) / 256), dim3(256), 0, stream>>>(pmax, rnorm, prm);
    k_small<<<dim3(B_DIM), dim3(512), 0, stream>>>(image_embeds, text_embeds, ier,
        a_w1, a_w2, r_w1, r_b1, r_g2, r_be2, r_w2, r_b2, r_g3, r_be3, r_w3, r_b3,
        h_w1, h_b1, h_g2, h_be2, h_w2, h_b2, h_g3, h_be3, h_w3, h_b3,
        prm, heat, out_f);
    k_resize<<<dim3(B_DIM * 8), dim3(256), 0, stream>>>(heat, out_f + B_DIM);
}